// Round 1
// baseline (1756.075 us; speedup 1.0000x reference)
//
#include <hip/hip_runtime.h>
#include <math.h>

#define N_HEADC  16
#define D_MODELC 1024
#define ATTN_N_C    3145728
#define ATTN_PAD_C  4194304
#define ATTN_KEEP_C 524288
#define PROJ_N_C    1048576
#define PROJ_PAD_C  1048576
#define PROJ_KEEP_C 131072
#define BATCH_C 2
#define SEQ_C   2048

// ---------------------------------------------------------------------------
// Scatter kept complex coeffs into zeroed full spectrum with hermitian mirror.
// Y[k] = re + i*im ; Y[N-k] = conj for k not in {0, N/2}. Indices are unique.
// ---------------------------------------------------------------------------
__global__ void scatter_herm(const float* __restrict__ re, const float* __restrict__ im,
                             const int* __restrict__ idx, float2* __restrict__ Y,
                             int keep, int N) {
    int t = blockIdx.x * blockDim.x + threadIdx.x;
    if (t >= keep) return;
    int k = idx[t];
    float r = re[t], i = im[t];
    Y[k] = make_float2(r, i);
    if (k != 0 && k != (N >> 1)) Y[N - k] = make_float2(r, -i);
}

// ---------------------------------------------------------------------------
// One Stockham radix-2 stage of the (unnormalized) INVERSE complex FFT.
// Stage s (=2^slog), m = N/(2s). t in [0, N/2): q = t & (s-1), p = t >> slog.
//   y[q + s*2p]     = a + b
//   y[q + s*(2p+1)] = (a - b) * e^{+i*pi*p/m}
// Autosorting: after log2(N) stages output is in natural order.
// ---------------------------------------------------------------------------
__global__ void fft_stage(const float2* __restrict__ in, float2* __restrict__ out,
                          int slog, int m, int half) {
    int t = blockIdx.x * blockDim.x + threadIdx.x;
    if (t >= half) return;
    int s = 1 << slog;
    int q = t & (s - 1);
    int p = t >> slog;
    // twiddle: e^{+i * pi * p / m}  (inverse transform)
    double ang = (M_PI / (double)m) * (double)p;
    float si, co;
    sincosf((float)ang, &si, &co);
    float2 a = in[q + s * p];
    float2 b = in[q + s * (p + m)];
    float2 su = make_float2(a.x + b.x, a.y + b.y);
    float2 di = make_float2(a.x - b.x, a.y - b.y);
    int ob = q + ((s << 1) * p);
    out[ob]     = su;
    out[ob + s] = make_float2(di.x * co - di.y * si, di.x * si + di.y * co);
}

// ---------------------------------------------------------------------------
// W[i] = Re(buf[i]) * (scale / N_pad)   (first n elements only)
// ---------------------------------------------------------------------------
__global__ void extract_real(const float2* __restrict__ buf, float* __restrict__ w,
                             int n, float inv_n, const float* __restrict__ scale) {
    int i = blockIdx.x * blockDim.x + threadIdx.x;
    if (i >= n) return;
    w[i] = buf[i].x * inv_n * scale[0];
}

// ---------------------------------------------------------------------------
// C[M,N] = A[M,K] @ B[K,N] + bias[N].  64x64 tile, 256 threads, 4x4 per thread.
// Dims assumed multiples of 64 (4096x3072x1024 and 4096x1024x1024 here).
// ---------------------------------------------------------------------------
__global__ __launch_bounds__(256) void gemm_bias_64(
    const float* __restrict__ A, const float* __restrict__ B,
    const float* __restrict__ bias, float* __restrict__ C,
    int M, int N, int K) {
    __shared__ float As[64][17];   // [row][k], padded
    __shared__ float Bs[16][64];   // [k][col]
    const int tid = threadIdx.x;
    const int tx = tid & 15, ty = tid >> 4;
    const int row0 = blockIdx.y * 64;
    const int col0 = blockIdx.x * 64;
    const int a_row = tid >> 2;          // 0..63
    const int a_col = (tid & 3) << 2;    // 0,4,8,12
    const int b_row = tid >> 4;          // 0..15
    const int b_col = (tid & 15) << 2;   // 0..60
    float acc[4][4] = {};
    for (int k0 = 0; k0 < K; k0 += 16) {
        float4 av = *(const float4*)(A + (size_t)(row0 + a_row) * K + k0 + a_col);
        float4 bv = *(const float4*)(B + (size_t)(k0 + b_row) * N + col0 + b_col);
        As[a_row][a_col + 0] = av.x; As[a_row][a_col + 1] = av.y;
        As[a_row][a_col + 2] = av.z; As[a_row][a_col + 3] = av.w;
        *(float4*)&Bs[b_row][b_col] = bv;
        __syncthreads();
#pragma unroll
        for (int kk = 0; kk < 16; ++kk) {
            float a0 = As[ty * 4 + 0][kk], a1 = As[ty * 4 + 1][kk];
            float a2 = As[ty * 4 + 2][kk], a3 = As[ty * 4 + 3][kk];
            float b0 = Bs[kk][tx * 4 + 0], b1 = Bs[kk][tx * 4 + 1];
            float b2 = Bs[kk][tx * 4 + 2], b3 = Bs[kk][tx * 4 + 3];
            acc[0][0] += a0 * b0; acc[0][1] += a0 * b1; acc[0][2] += a0 * b2; acc[0][3] += a0 * b3;
            acc[1][0] += a1 * b0; acc[1][1] += a1 * b1; acc[1][2] += a1 * b2; acc[1][3] += a1 * b3;
            acc[2][0] += a2 * b0; acc[2][1] += a2 * b1; acc[2][2] += a2 * b2; acc[2][3] += a2 * b3;
            acc[3][0] += a3 * b0; acc[3][1] += a3 * b1; acc[3][2] += a3 * b2; acc[3][3] += a3 * b3;
        }
        __syncthreads();
    }
    float bv0 = bias[col0 + tx * 4 + 0], bv1 = bias[col0 + tx * 4 + 1];
    float bv2 = bias[col0 + tx * 4 + 2], bv3 = bias[col0 + tx * 4 + 3];
#pragma unroll
    for (int i = 0; i < 4; ++i) {
        float* cp = C + (size_t)(row0 + ty * 4 + i) * N + col0 + tx * 4;
        cp[0] = acc[i][0] + bv0; cp[1] = acc[i][1] + bv1;
        cp[2] = acc[i][2] + bv2; cp[3] = acc[i][3] + bv3;
    }
}

// ---------------------------------------------------------------------------
// Flash-style attention. qkv: [B,S,3*D] with q|k|v each D=1024, head dim 64.
// One block per (q-tile of 64 rows, head, batch). Online softmax.
// ctx out: [B,S,D].
// ---------------------------------------------------------------------------
__global__ __launch_bounds__(256) void attn_fwd(
    const float* __restrict__ qkv, float* __restrict__ ctx) {
    const int qb = blockIdx.x, h = blockIdx.y, b = blockIdx.z;
    const int tid = threadIdx.x;
    const int tx = tid & 15, ty = tid >> 4;

    __shared__ float Qs[64][65];
    __shared__ float Ks[64][65];
    __shared__ float Vs[64][65];
    __shared__ float Ps[64][65];
    __shared__ float m_s[64], l_s[64], al_s[64];

    const size_t bb = (size_t)b * SEQ_C * 3072;
    const float* qbase = qkv + bb + h * 64;
    const float* kbase = qkv + bb + 1024 + h * 64;
    const float* vbase = qkv + bb + 2048 + h * 64;

    // load Q tile (64 rows x 64 dims)
    for (int i = tid; i < 64 * 16; i += 256) {
        int r = i >> 4, c4 = (i & 15) << 2;
        float4 v = *(const float4*)(qbase + (size_t)(qb * 64 + r) * 3072 + c4);
        Qs[r][c4] = v.x; Qs[r][c4 + 1] = v.y; Qs[r][c4 + 2] = v.z; Qs[r][c4 + 3] = v.w;
    }
    if (tid < 64) { m_s[tid] = -1e30f; l_s[tid] = 0.f; }
    float acc[4][4] = {};

    for (int kt = 0; kt < SEQ_C / 64; ++kt) {
        __syncthreads();   // Q ready (iter 0); Ks/Vs/Ps consumed (later iters)
        for (int i = tid; i < 64 * 16; i += 256) {
            int r = i >> 4, c4 = (i & 15) << 2;
            float4 kv = *(const float4*)(kbase + (size_t)(kt * 64 + r) * 3072 + c4);
            Ks[r][c4] = kv.x; Ks[r][c4 + 1] = kv.y; Ks[r][c4 + 2] = kv.z; Ks[r][c4 + 3] = kv.w;
            float4 vv = *(const float4*)(vbase + (size_t)(kt * 64 + r) * 3072 + c4);
            Vs[r][c4] = vv.x; Vs[r][c4 + 1] = vv.y; Vs[r][c4 + 2] = vv.z; Vs[r][c4 + 3] = vv.w;
        }
        __syncthreads();
        // S = Q K^T * 0.125
        float sacc[4][4] = {};
        for (int d = 0; d < 64; ++d) {
            float qa[4], kb[4];
#pragma unroll
            for (int ii = 0; ii < 4; ++ii) qa[ii] = Qs[ty * 4 + ii][d];
#pragma unroll
            for (int jj = 0; jj < 4; ++jj) kb[jj] = Ks[tx * 4 + jj][d];
#pragma unroll
            for (int ii = 0; ii < 4; ++ii)
#pragma unroll
                for (int jj = 0; jj < 4; ++jj) sacc[ii][jj] += qa[ii] * kb[jj];
        }
#pragma unroll
        for (int ii = 0; ii < 4; ++ii)
#pragma unroll
            for (int jj = 0; jj < 4; ++jj)
                Ps[ty * 4 + ii][tx * 4 + jj] = sacc[ii][jj] * 0.125f;
        __syncthreads();
        // online softmax row pass (one thread per q-row)
        if (tid < 64) {
            int i = tid;
            float mo = m_s[i];
            float mx = mo;
            for (int j = 0; j < 64; ++j) mx = fmaxf(mx, Ps[i][j]);
            float al = __expf(mo - mx);
            float sum = 0.f;
            for (int j = 0; j < 64; ++j) {
                float p = __expf(Ps[i][j] - mx);
                Ps[i][j] = p; sum += p;
            }
            l_s[i] = l_s[i] * al + sum;
            m_s[i] = mx;
            al_s[i] = al;
        }
        __syncthreads();
        // O = alpha*O + P @ V
#pragma unroll
        for (int ii = 0; ii < 4; ++ii) {
            float a = al_s[ty * 4 + ii];
#pragma unroll
            for (int jj = 0; jj < 4; ++jj) acc[ii][jj] *= a;
        }
        for (int k = 0; k < 64; ++k) {
            float pv[4], vv[4];
#pragma unroll
            for (int ii = 0; ii < 4; ++ii) pv[ii] = Ps[ty * 4 + ii][k];
#pragma unroll
            for (int jj = 0; jj < 4; ++jj) vv[jj] = Vs[k][tx * 4 + jj];
#pragma unroll
            for (int ii = 0; ii < 4; ++ii)
#pragma unroll
                for (int jj = 0; jj < 4; ++jj) acc[ii][jj] += pv[ii] * vv[jj];
        }
    }
#pragma unroll
    for (int ii = 0; ii < 4; ++ii) {
        float inv = 1.f / l_s[ty * 4 + ii];
        float* op = ctx + ((size_t)b * SEQ_C + qb * 64 + ty * 4 + ii) * 1024 + h * 64 + tx * 4;
#pragma unroll
        for (int jj = 0; jj < 4; ++jj) op[jj] = acc[ii][jj] * inv;
    }
}

// ---------------------------------------------------------------------------
// Workspace layout (bytes). Peak use 96 MB with region reuse:
//   A0:  0        .. 32M   (attn fft ping)   -> reused for qkv [0..48M)
//   A1:  32M      .. 64M   (attn fft pong)
//   P0:  64M      .. 72M   (proj fft ping)   -> reused for ctx [64M..80M)
//   P1:  72M      .. 80M
//   Wa:  80M      .. 92M
//   Wp:  92M      .. 96M
// ---------------------------------------------------------------------------
extern "C" void kernel_launch(void* const* d_in, const int* in_sizes, int n_in,
                              void* d_out, int out_size, void* d_ws, size_t ws_size,
                              hipStream_t stream) {
    const float* x        = (const float*)d_in[0];
    const float* attn_re  = (const float*)d_in[1];
    const float* attn_im  = (const float*)d_in[2];
    const int*   attn_idx = (const int*)d_in[3];
    const float* attn_sc  = (const float*)d_in[4];
    const float* proj_re  = (const float*)d_in[5];
    const float* proj_im  = (const float*)d_in[6];
    const int*   proj_idx = (const int*)d_in[7];
    const float* proj_sc  = (const float*)d_in[8];
    const float* attn_b   = (const float*)d_in[9];
    const float* proj_b   = (const float*)d_in[10];
    float* out = (float*)d_out;

    char* w = (char*)d_ws;
    float2* A0 = (float2*)(w);
    float2* A1 = (float2*)(w + (size_t)33554432);
    float2* P0 = (float2*)(w + (size_t)67108864);
    float2* P1 = (float2*)(w + (size_t)75497472);
    float*  Wa = (float*)(w + (size_t)83886080);
    float*  Wp = (float*)(w + (size_t)96468992);
    float*  qkvb = (float*)(w);                      // reuse A0+A1 after extract
    float*  ctx  = (float*)(w + (size_t)67108864);   // reuse P0+P1 after extract

    // zero full spectra, scatter kept coeffs (hermitian)
    hipMemsetAsync(A0, 0, (size_t)ATTN_PAD_C * 8, stream);
    hipMemsetAsync(P0, 0, (size_t)PROJ_PAD_C * 8, stream);
    scatter_herm<<<ATTN_KEEP_C / 256, 256, 0, stream>>>(attn_re, attn_im, attn_idx, A0, ATTN_KEEP_C, ATTN_PAD_C);
    scatter_herm<<<PROJ_KEEP_C / 256, 256, 0, stream>>>(proj_re, proj_im, proj_idx, P0, PROJ_KEEP_C, PROJ_PAD_C);

    // inverse FFT, attn: 22 stages, ends in A0
    {
        float2* bufs[2] = {A0, A1};
        int half = ATTN_PAD_C / 2;
        for (int st = 0; st < 22; ++st) {
            int m = ATTN_PAD_C >> (st + 1);
            fft_stage<<<half / 256, 256, 0, stream>>>(bufs[st & 1], bufs[1 - (st & 1)], st, m, half);
        }
    }
    // inverse FFT, proj: 20 stages, ends in P0
    {
        float2* bufs[2] = {P0, P1};
        int half = PROJ_PAD_C / 2;
        for (int st = 0; st < 20; ++st) {
            int m = PROJ_PAD_C >> (st + 1);
            fft_stage<<<half / 256, 256, 0, stream>>>(bufs[st & 1], bufs[1 - (st & 1)], st, m, half);
        }
    }

    extract_real<<<ATTN_N_C / 256, 256, 0, stream>>>(A0, Wa, ATTN_N_C, 1.f / ATTN_PAD_C, attn_sc);
    extract_real<<<PROJ_N_C / 256, 256, 0, stream>>>(P0, Wp, PROJ_N_C, 1.f / PROJ_PAD_C, proj_sc);

    // qkv = x @ Wa + attn_bias : [4096,1024]@[1024,3072]
    gemm_bias_64<<<dim3(3072 / 64, 4096 / 64), 256, 0, stream>>>(x, Wa, attn_b, qkvb, 4096, 3072, 1024);

    // attention
    attn_fwd<<<dim3(SEQ_C / 64, N_HEADC, BATCH_C), 256, 0, stream>>>(qkvb, ctx);

    // out = ctx @ Wp + proj_bias : [4096,1024]@[1024,1024]
    gemm_bias_64<<<dim3(1024 / 64, 4096 / 64), 256, 0, stream>>>(ctx, Wp, proj_b, out, 4096, 1024, 1024);
}

// Round 2
// 678.711 us; speedup vs baseline: 2.5874x; 2.5874x over previous
//
#include <hip/hip_runtime.h>
#include <math.h>

#define N_HEADC  16
#define D_MODELC 1024
#define ATTN_N_C    3145728
#define ATTN_PAD_C  4194304
#define ATTN_KEEP_C 524288
#define PROJ_N_C    1048576
#define PROJ_PAD_C  1048576
#define PROJ_KEEP_C 131072
#define BATCH_C 2
#define SEQ_C   2048

typedef __attribute__((ext_vector_type(8))) short s16x8;
typedef __attribute__((ext_vector_type(4))) float f32x4;

static __device__ __forceinline__ ushort f2bf(float f) {
    __bf16 b = (__bf16)f;
    return __builtin_bit_cast(ushort, b);
}

// ---------------------------------------------------------------------------
// Scatter kept complex coeffs into zeroed full spectrum with hermitian mirror.
// ---------------------------------------------------------------------------
__global__ void scatter_herm(const float* __restrict__ re, const float* __restrict__ im,
                             const int* __restrict__ idx, float2* __restrict__ Y,
                             int keep, int N) {
    int t = blockIdx.x * blockDim.x + threadIdx.x;
    if (t >= keep) return;
    int k = idx[t];
    float r = re[t], i = im[t];
    Y[k] = make_float2(r, i);
    if (k != 0 && k != (N >> 1)) Y[N - k] = make_float2(r, -i);
}

// ---------------------------------------------------------------------------
// One Stockham radix-2 stage of the (unnormalized) INVERSE complex FFT.
// ---------------------------------------------------------------------------
__global__ void fft_stage(const float2* __restrict__ in, float2* __restrict__ out,
                          int slog, int m, int half) {
    int t = blockIdx.x * blockDim.x + threadIdx.x;
    if (t >= half) return;
    int s = 1 << slog;
    int q = t & (s - 1);
    int p = t >> slog;
    double ang = (M_PI / (double)m) * (double)p;
    float si, co;
    sincosf((float)ang, &si, &co);
    float2 a = in[q + s * p];
    float2 b = in[q + s * (p + m)];
    float2 su = make_float2(a.x + b.x, a.y + b.y);
    float2 di = make_float2(a.x - b.x, a.y - b.y);
    int ob = q + ((s << 1) * p);
    out[ob]     = su;
    out[ob + s] = make_float2(di.x * co - di.y * si, di.x * si + di.y * co);
}

// ---------------------------------------------------------------------------
// Tiled transpose + bf16 cast of decompressed weight.
// W (conceptual) is [Kd rows][Nd cols], element k,n = buf[k*Nd+n].x * inv * scale.
// Writes WT[n][k] (bf16, row-major [Nd][Kd]) for the GEMM's B^T operand.
// ---------------------------------------------------------------------------
__global__ __launch_bounds__(256) void transpose_w_bf16(
    const float2* __restrict__ buf, ushort* __restrict__ WT,
    int Kd, int Nd, float inv, const float* __restrict__ sc) {
    __shared__ float T[32][33];
    const int n0 = blockIdx.x * 32, k0 = blockIdx.y * 32;
    const int tx = threadIdx.x & 31, ty = threadIdx.x >> 5;
    const float s = inv * sc[0];
    for (int r = ty; r < 32; r += 8)
        T[r][tx] = buf[(size_t)(k0 + r) * Nd + n0 + tx].x;
    __syncthreads();
    for (int r = ty; r < 32; r += 8)
        WT[(size_t)(n0 + r) * Kd + k0 + tx] = f2bf(T[tx][r] * s);
}

// ---------------------------------------------------------------------------
// x (fp32) -> bf16
// ---------------------------------------------------------------------------
__global__ void x_to_bf16(const float* __restrict__ x, ushort* __restrict__ xb, int n4) {
    int i = blockIdx.x * blockDim.x + threadIdx.x;
    if (i >= n4) return;
    float4 v = *(const float4*)(x + (size_t)i * 4);
    ushort4 o;
    o.x = f2bf(v.x); o.y = f2bf(v.y); o.z = f2bf(v.z); o.w = f2bf(v.w);
    *(ushort4*)(xb + (size_t)i * 4) = o;
}

// ---------------------------------------------------------------------------
// bf16 MFMA GEMM: C[M,N] = A[M,K] @ Bt[N,K]^T + bias.
// 128x128 tile, BK=32, 4 waves, each wave 64x64 (4x4 MFMA frags of 16x16x32).
// OUTMODE 0: C fp32.
// OUTMODE 1: qkv epilogue — cols [0,2048) stored bf16 to C; cols [2048,3072)
//            (the V third) stored TRANSPOSED per batch to Vt[b][d][seq] bf16.
// ---------------------------------------------------------------------------
template <int OUTMODE>
__global__ __launch_bounds__(256) void gemm_bt_mfma(
    const ushort* __restrict__ A, const ushort* __restrict__ Bt,
    const float* __restrict__ bias, void* __restrict__ Cout,
    ushort* __restrict__ Vt, int M, int N, int K) {
    __shared__ ushort As[128 * 40];   // [row][k] padded 32->40
    __shared__ ushort Bs[128 * 40];   // [col][k] padded
    const int tid = threadIdx.x;
    const int wid = tid >> 6, lane = tid & 63, quad = lane >> 4, l16 = lane & 15;
    const int row0 = blockIdx.y * 128, col0 = blockIdx.x * 128;
    const int mh = (wid >> 1) * 64, nh = (wid & 1) * 64;

    f32x4 acc[4][4] = {};

    for (int k0 = 0; k0 < K; k0 += 32) {
        __syncthreads();
#pragma unroll
        for (int rep = 0; rep < 2; ++rep) {
            int c = tid + rep * 256;          // 0..511
            int r = c >> 2, co = (c & 3) * 8; // 4 chunks (of 8 bf16) per row
            uint4 va = *(const uint4*)(A + (size_t)(row0 + r) * K + k0 + co);
            *(uint4*)&As[r * 40 + co] = va;
            uint4 vb = *(const uint4*)(Bt + (size_t)(col0 + r) * K + k0 + co);
            *(uint4*)&Bs[r * 40 + co] = vb;
        }
        __syncthreads();
        s16x8 af[4], bfr[4];
#pragma unroll
        for (int mi = 0; mi < 4; ++mi)
            af[mi] = *(const s16x8*)&As[(mh + mi * 16 + l16) * 40 + quad * 8];
#pragma unroll
        for (int ni = 0; ni < 4; ++ni)
            bfr[ni] = *(const s16x8*)&Bs[(nh + ni * 16 + l16) * 40 + quad * 8];
#pragma unroll
        for (int mi = 0; mi < 4; ++mi)
#pragma unroll
            for (int ni = 0; ni < 4; ++ni)
                acc[mi][ni] = __builtin_amdgcn_mfma_f32_16x16x32_bf16(
                    af[mi], bfr[ni], acc[mi][ni], 0, 0, 0);
    }

#pragma unroll
    for (int mi = 0; mi < 4; ++mi)
#pragma unroll
        for (int ni = 0; ni < 4; ++ni) {
            const int col = col0 + nh + ni * 16 + l16;
            const int rbase = row0 + mh + mi * 16 + quad * 4;
            const float bv = bias[col];
            if (OUTMODE == 0) {
                float* C = (float*)Cout;
#pragma unroll
                for (int j = 0; j < 4; ++j)
                    C[(size_t)(rbase + j) * N + col] = acc[mi][ni][j] + bv;
            } else {
                if (col < 2048) {
                    ushort* C = (ushort*)Cout;
#pragma unroll
                    for (int j = 0; j < 4; ++j)
                        C[(size_t)(rbase + j) * N + col] = f2bf(acc[mi][ni][j] + bv);
                } else {
                    const int bb = rbase >> 11;       // batch
                    const int seq = rbase & 2047;     // multiple of 4
                    const int d = col - 2048;
                    ushort4 pk;
                    pk.x = f2bf(acc[mi][ni][0] + bv);
                    pk.y = f2bf(acc[mi][ni][1] + bv);
                    pk.z = f2bf(acc[mi][ni][2] + bv);
                    pk.w = f2bf(acc[mi][ni][3] + bv);
                    *(ushort4*)&Vt[(size_t)bb * 2097152 + (size_t)d * 2048 + seq] = pk;
                }
            }
        }
}

// ---------------------------------------------------------------------------
// MFMA flash attention. qkv: [B*S, 3072] bf16 (Q cols 0..1023, K cols 1024..2047,
// V third not used here). Vt: [B][1024 d][2048 seq] bf16 (pre-transposed).
// Block: 128 Q-rows x 1 head x 1 batch; 4 waves, each 32 Q-rows.
// ctx out: [B*S, 1024] bf16.
// ---------------------------------------------------------------------------
__global__ __launch_bounds__(256) void attn_fwd_mfma(
    const ushort* __restrict__ qkv, const ushort* __restrict__ Vt,
    ushort* __restrict__ ctx) {
    const int qb = blockIdx.x, h = blockIdx.y, b = blockIdx.z;
    const int tid = threadIdx.x;
    const int wid = tid >> 6, lane = tid & 63, quad = lane >> 4, l16 = lane & 15;

    __shared__ ushort Qs[128 * 72];
    __shared__ ushort Ks[64 * 72];
    __shared__ ushort Vts[64 * 72];   // [d][kpos]
    __shared__ ushort Ps[128 * 72];

    // stage Q tile: 128 rows x 64 cols (= head h slice of Q region)
#pragma unroll
    for (int rep = 0; rep < 4; ++rep) {
        int c = tid + rep * 256;          // 1024 chunks of 8 bf16
        int r = c >> 3, co = (c & 7) * 8;
        uint4 v = *(const uint4*)(qkv + (size_t)(b * 2048 + qb * 128 + r) * 3072 + h * 64 + co);
        *(uint4*)&Qs[r * 72 + co] = v;
    }

    f32x4 o[2][4] = {};
    float m_r[2][4], l_r[2][4];
#pragma unroll
    for (int mi = 0; mi < 2; ++mi)
#pragma unroll
        for (int j = 0; j < 4; ++j) { m_r[mi][j] = -1e30f; l_r[mi][j] = 0.f; }

    for (int kt = 0; kt < SEQ_C / 64; ++kt) {
        __syncthreads();   // prev PV done; safe to overwrite Ks/Vts (also Q ready)
        // stage K tile [64 kpos][64 d] and Vt tile [64 d][64 kpos]
#pragma unroll
        for (int rep = 0; rep < 2; ++rep) {
            int c = tid + rep * 256;      // 512 chunks
            int r = c >> 3, co = (c & 7) * 8;
            uint4 kv = *(const uint4*)(qkv + (size_t)(b * 2048 + kt * 64 + r) * 3072 + 1024 + h * 64 + co);
            *(uint4*)&Ks[r * 72 + co] = kv;
            uint4 vv = *(const uint4*)(Vt + (size_t)b * 2097152 + (size_t)(h * 64 + r) * 2048 + kt * 64 + co);
            *(uint4*)&Vts[r * 72 + co] = vv;
        }
        __syncthreads();

        // S = Q K^T
        f32x4 s[2][4] = {};
#pragma unroll
        for (int ks = 0; ks < 2; ++ks) {
            s16x8 qa[2], kb[4];
#pragma unroll
            for (int mi = 0; mi < 2; ++mi)
                qa[mi] = *(const s16x8*)&Qs[(wid * 32 + mi * 16 + l16) * 72 + ks * 32 + quad * 8];
#pragma unroll
            for (int ni = 0; ni < 4; ++ni)
                kb[ni] = *(const s16x8*)&Ks[(ni * 16 + l16) * 72 + ks * 32 + quad * 8];
#pragma unroll
            for (int mi = 0; mi < 2; ++mi)
#pragma unroll
                for (int ni = 0; ni < 4; ++ni)
                    s[mi][ni] = __builtin_amdgcn_mfma_f32_16x16x32_bf16(
                        qa[mi], kb[ni], s[mi][ni], 0, 0, 0);
        }
#pragma unroll
        for (int mi = 0; mi < 2; ++mi)
#pragma unroll
            for (int ni = 0; ni < 4; ++ni)
                s[mi][ni] *= 0.125f;   // 1/sqrt(64)

        // online softmax; write P (bf16) to LDS in A-operand layout
#pragma unroll
        for (int mi = 0; mi < 2; ++mi)
#pragma unroll
            for (int j = 0; j < 4; ++j) {
                float rm = fmaxf(fmaxf(s[mi][0][j], s[mi][1][j]),
                                 fmaxf(s[mi][2][j], s[mi][3][j]));
#pragma unroll
                for (int off = 1; off < 16; off <<= 1)
                    rm = fmaxf(rm, __shfl_xor(rm, off));
                const float mo = m_r[mi][j];
                const float mn = fmaxf(mo, rm);
                const float al = __expf(mo - mn);
                float ps = 0.f;
#pragma unroll
                for (int ni = 0; ni < 4; ++ni) {
                    float p = __expf(s[mi][ni][j] - mn);
                    s[mi][ni][j] = p;
                    ps += p;
                }
#pragma unroll
                for (int off = 1; off < 16; off <<= 1)
                    ps += __shfl_xor(ps, off);
                l_r[mi][j] = l_r[mi][j] * al + ps;
                m_r[mi][j] = mn;
#pragma unroll
                for (int nd = 0; nd < 4; ++nd) o[mi][nd][j] *= al;
                const int pr = wid * 32 + mi * 16 + quad * 4 + j;
#pragma unroll
                for (int ni = 0; ni < 4; ++ni)
                    Ps[pr * 72 + ni * 16 + l16] = f2bf(s[mi][ni][j]);
            }
        __syncthreads();   // P visible (and K/V stage fully consumed)

        // O += P @ V   (B operand = V^T tile: [d][kpos])
#pragma unroll
        for (int ks = 0; ks < 2; ++ks) {
            s16x8 pa[2], vb[4];
#pragma unroll
            for (int mi = 0; mi < 2; ++mi)
                pa[mi] = *(const s16x8*)&Ps[(wid * 32 + mi * 16 + l16) * 72 + ks * 32 + quad * 8];
#pragma unroll
            for (int nd = 0; nd < 4; ++nd)
                vb[nd] = *(const s16x8*)&Vts[(nd * 16 + l16) * 72 + ks * 32 + quad * 8];
#pragma unroll
            for (int mi = 0; mi < 2; ++mi)
#pragma unroll
                for (int nd = 0; nd < 4; ++nd)
                    o[mi][nd] = __builtin_amdgcn_mfma_f32_16x16x32_bf16(
                        pa[mi], vb[nd], o[mi][nd], 0, 0, 0);
        }
    }

    // epilogue: ctx[row][h*64 + d] = O / l
#pragma unroll
    for (int mi = 0; mi < 2; ++mi)
#pragma unroll
        for (int j = 0; j < 4; ++j) {
            const float inv = 1.f / l_r[mi][j];
            const size_t row = (size_t)(b * 2048 + qb * 128 + wid * 32 + mi * 16 + quad * 4 + j);
#pragma unroll
            for (int nd = 0; nd < 4; ++nd)
                ctx[row * 1024 + h * 64 + nd * 16 + l16] = f2bf(o[mi][nd][j] * inv);
        }
}

// ---------------------------------------------------------------------------
// Workspace layout (96 MB total):
//   [0,   32M)  A0 (attn fft ping)      -> reused: qkv bf16 [4096][3072] (25.2M)
//   [32M, 64M)  A1 (attn fft pong)      -> reused: Vt bf16 [2][1024][2048] (8M)
//   [64M, 72M)  P0 (proj fft ping)      -> reused: ctx bf16 [4096][1024] (8M)
//   [72M, 80M)  P1 (proj fft pong)
//   [80M, 86M)  WaT bf16 [3072][1024]
//   [86M, 88M)  WpT bf16 [1024][1024]
//   [88M, 96M)  x_bf bf16 [4096][1024]
// ---------------------------------------------------------------------------
extern "C" void kernel_launch(void* const* d_in, const int* in_sizes, int n_in,
                              void* d_out, int out_size, void* d_ws, size_t ws_size,
                              hipStream_t stream) {
    const float* x        = (const float*)d_in[0];
    const float* attn_re  = (const float*)d_in[1];
    const float* attn_im  = (const float*)d_in[2];
    const int*   attn_idx = (const int*)d_in[3];
    const float* attn_sc  = (const float*)d_in[4];
    const float* proj_re  = (const float*)d_in[5];
    const float* proj_im  = (const float*)d_in[6];
    const int*   proj_idx = (const int*)d_in[7];
    const float* proj_sc  = (const float*)d_in[8];
    const float* attn_b   = (const float*)d_in[9];
    const float* proj_b   = (const float*)d_in[10];
    float* out = (float*)d_out;

    char* w = (char*)d_ws;
    float2* A0  = (float2*)(w);
    float2* A1  = (float2*)(w + (size_t)33554432);
    float2* P0  = (float2*)(w + (size_t)67108864);
    float2* P1  = (float2*)(w + (size_t)75497472);
    ushort* WaT = (ushort*)(w + (size_t)83886080);
    ushort* WpT = (ushort*)(w + (size_t)90177536);
    ushort* x_bf= (ushort*)(w + (size_t)92274688);
    ushort* qkvb= (ushort*)(w);                      // after attn FFT + WaT done
    ushort* Vt  = (ushort*)(w + (size_t)33554432);   // after attn FFT done
    ushort* ctx = (ushort*)(w + (size_t)67108864);   // after proj FFT + WpT done

    // x -> bf16 (independent of FFT work)
    x_to_bf16<<<4096, 256, 0, stream>>>(x, x_bf, 1048576);

    // zero spectra + hermitian scatter
    hipMemsetAsync(A0, 0, (size_t)ATTN_PAD_C * 8, stream);
    hipMemsetAsync(P0, 0, (size_t)PROJ_PAD_C * 8, stream);
    scatter_herm<<<ATTN_KEEP_C / 256, 256, 0, stream>>>(attn_re, attn_im, attn_idx, A0, ATTN_KEEP_C, ATTN_PAD_C);
    scatter_herm<<<PROJ_KEEP_C / 256, 256, 0, stream>>>(proj_re, proj_im, proj_idx, P0, PROJ_KEEP_C, PROJ_PAD_C);

    // inverse FFT attn: 22 radix-2 stages, ends in A0
    {
        float2* bufs[2] = {A0, A1};
        int half = ATTN_PAD_C / 2;
        for (int st = 0; st < 22; ++st) {
            int m = ATTN_PAD_C >> (st + 1);
            fft_stage<<<half / 256, 256, 0, stream>>>(bufs[st & 1], bufs[1 - (st & 1)], st, m, half);
        }
    }
    // WaT[n][k] bf16 (reads A0; must precede qkv GEMM which overwrites region 0)
    transpose_w_bf16<<<dim3(3072 / 32, 1024 / 32), 256, 0, stream>>>(
        A0, WaT, 1024, 3072, 1.f / ATTN_PAD_C, attn_sc);

    // inverse FFT proj: 20 stages, ends in P0
    {
        float2* bufs[2] = {P0, P1};
        int half = PROJ_PAD_C / 2;
        for (int st = 0; st < 20; ++st) {
            int m = PROJ_PAD_C >> (st + 1);
            fft_stage<<<half / 256, 256, 0, stream>>>(bufs[st & 1], bufs[1 - (st & 1)], st, m, half);
        }
    }
    transpose_w_bf16<<<dim3(1024 / 32, 1024 / 32), 256, 0, stream>>>(
        P0, WpT, 1024, 1024, 1.f / PROJ_PAD_C, proj_sc);

    // qkv = x @ Wa + bias  (bf16 out; V third written transposed into Vt)
    gemm_bt_mfma<1><<<dim3(3072 / 128, 4096 / 128), 256, 0, stream>>>(
        x_bf, WaT, attn_b, qkvb, Vt, 4096, 3072, 1024);

    // flash attention (MFMA)
    attn_fwd_mfma<<<dim3(SEQ_C / 128, N_HEADC, BATCH_C), 256, 0, stream>>>(qkvb, Vt, ctx);

    // out = ctx @ Wp + bias (fp32 out)
    gemm_bt_mfma<0><<<dim3(1024 / 128, 4096 / 128), 256, 0, stream>>>(
        ctx, WpT, proj_b, out, (ushort*)nullptr, 4096, 1024, 1024);
}

// Round 3
// 448.029 us; speedup vs baseline: 3.9196x; 1.5149x over previous
//
#include <hip/hip_runtime.h>
#include <math.h>

#define N_HEADC  16
#define D_MODELC 1024
#define ATTN_N_C    3145728
#define ATTN_PAD_C  4194304
#define ATTN_NC     2097152   // half-size complex FFT length (2^21)
#define ATTN_KEEP_C 524288
#define PROJ_N_C    1048576
#define PROJ_PAD_C  1048576
#define PROJ_NC     524288    // 2^19
#define PROJ_KEEP_C 131072
#define BATCH_C 2
#define SEQ_C   2048

typedef __attribute__((ext_vector_type(8))) short s16x8;
typedef __attribute__((ext_vector_type(4))) float f32x4;

static __device__ __forceinline__ ushort f2bf(float f) {
    __bf16 b = (__bf16)f;
    return __builtin_bit_cast(ushort, b);
}
static __device__ __forceinline__ float2 cmul(float2 a, float2 b) {
    return make_float2(a.x * b.x - a.y * b.y, a.x * b.y + a.y * b.x);
}

// ---------------------------------------------------------------------------
// Scatter kept coeffs into zeroed HALF spectrum H[0..Nc] (no mirror needed).
// ---------------------------------------------------------------------------
__global__ void scatter_half(const float* __restrict__ re, const float* __restrict__ im,
                             const int* __restrict__ idx, float2* __restrict__ H, int keep) {
    int t = blockIdx.x * blockDim.x + threadIdx.x;
    if (t >= keep) return;
    H[idx[t]] = make_float2(re[t], im[t]);
}

// ---------------------------------------------------------------------------
// Pack half-spectrum H (len Nc+1) into Z (len Nc) for the half-size complex
// inverse FFT:  Z[k] = (H[k]+conj(H[Nc-k])) + i*e^{2pi i k/(2Nc)}*(H[k]-conj(H[Nc-k]))
// Imag of DC/Nyquist zeroed (they only affect Im(x), which irfft discards).
// ---------------------------------------------------------------------------
__global__ void pack_z(const float2* __restrict__ H, float2* __restrict__ Z,
                       int Nc, float th0) {
    int k = blockIdx.x * blockDim.x + threadIdx.x;
    if (k >= Nc) return;
    float2 g = H[k];
    float2 hm = H[Nc - k];
    if (k == 0) { g.y = 0.f; hm.y = 0.f; }
    float2 gh = make_float2(hm.x, -hm.y);          // conj
    float2 sum = make_float2(g.x + gh.x, g.y + gh.y);
    float2 dif = make_float2(g.x - gh.x, g.y - gh.y);
    float si, co;
    sincosf(th0 * (float)k, &si, &co);
    float2 t = make_float2(dif.x * co - dif.y * si, dif.x * si + dif.y * co); // w*dif
    Z[k] = make_float2(sum.x - t.y, sum.y + t.x);  // sum + i*(w*dif)
}

// ---------------------------------------------------------------------------
// Radix-2 Stockham inverse stage (used once since log2(Nc) is odd).
// ---------------------------------------------------------------------------
__global__ void fft_stage(const float2* __restrict__ in, float2* __restrict__ out,
                          int slog, int m, int half) {
    int t = blockIdx.x * blockDim.x + threadIdx.x;
    if (t >= half) return;
    int s = 1 << slog;
    int q = t & (s - 1);
    int p = t >> slog;
    float si, co;
    sincosf((float)(M_PI / (double)m) * (float)p, &si, &co);
    float2 a = in[q + s * p];
    float2 b = in[q + s * (p + m)];
    float2 su = make_float2(a.x + b.x, a.y + b.y);
    float2 di = make_float2(a.x - b.x, a.y - b.y);
    int ob = q + ((s << 1) * p);
    out[ob]     = su;
    out[ob + s] = make_float2(di.x * co - di.y * si, di.x * si + di.y * co);
}

// ---------------------------------------------------------------------------
// Radix-4 Stockham inverse stage. s=2^slog, M = Nc/(4s), quarter = Nc/4.
//   in:  u[q + s*(p + j*M)], j=0..3 ; out: y[q + 4sp + j*s]
//   w = e^{+2pi i p/(4M)} = e^{+i*ang0*p}, ang0 = pi/(2M)
//   y0 = (A0+A2)+(A1+A3); y1 = w((A0-A2)+i(A1-A3));
//   y2 = w^2((A0+A2)-(A1+A3)); y3 = w^3((A0-A2)-i(A1-A3))
// ---------------------------------------------------------------------------
__global__ void fft_stage_r4(const float2* __restrict__ in, float2* __restrict__ out,
                             int slog, int M, float ang0, int quarter) {
    int t = blockIdx.x * blockDim.x + threadIdx.x;
    if (t >= quarter) return;
    int s = 1 << slog;
    int q = t & (s - 1);
    int p = t >> slog;
    float2 a0 = in[q + s * p];
    float2 a1 = in[q + s * (p + M)];
    float2 a2 = in[q + s * (p + 2 * M)];
    float2 a3 = in[q + s * (p + 3 * M)];
    float si, co;
    sincosf(ang0 * (float)p, &si, &co);
    float2 w  = make_float2(co, si);
    float2 w2 = cmul(w, w);
    float2 w3 = cmul(w2, w);
    float2 t0 = make_float2(a0.x + a2.x, a0.y + a2.y);
    float2 t1 = make_float2(a0.x - a2.x, a0.y - a2.y);
    float2 t2 = make_float2(a1.x + a3.x, a1.y + a3.y);
    float2 t3 = make_float2(a1.x - a3.x, a1.y - a3.y);
    float2 t3i = make_float2(-t3.y, t3.x);
    int ob = q + 4 * s * p;
    out[ob]         = make_float2(t0.x + t2.x, t0.y + t2.y);
    out[ob + s]     = cmul(w,  make_float2(t1.x + t3i.x, t1.y + t3i.y));
    out[ob + 2 * s] = cmul(w2, make_float2(t0.x - t2.x, t0.y - t2.y));
    out[ob + 3 * s] = cmul(w3, make_float2(t1.x - t3i.x, t1.y - t3i.y));
}

// ---------------------------------------------------------------------------
// Fused unpack + transpose + bf16 cast.
// W (conceptual) [Kd][Nd], element (k,n): j=k*Nd+n, x[j] = (j even ? Re : Im) z[j>>1].
// Writes WT[n][k] bf16.
// ---------------------------------------------------------------------------
__global__ __launch_bounds__(256) void transpose_wz_bf16(
    const float2* __restrict__ z, ushort* __restrict__ WT,
    int Kd, int Nd, float inv, const float* __restrict__ sc) {
    __shared__ float T[32][33];
    const int n0 = blockIdx.x * 32, k0 = blockIdx.y * 32;
    const int tx = threadIdx.x & 31, ty = threadIdx.x >> 5;
    const float s = inv * sc[0];
    for (int r = ty; r < 32; r += 8) {
        size_t j = (size_t)(k0 + r) * Nd + n0 + tx;
        float2 zz = z[j >> 1];
        T[r][tx] = (j & 1) ? zz.y : zz.x;
    }
    __syncthreads();
    for (int r = ty; r < 32; r += 8)
        WT[(size_t)(n0 + r) * Kd + k0 + tx] = f2bf(T[tx][r] * s);
}

// ---------------------------------------------------------------------------
// x (fp32) -> bf16
// ---------------------------------------------------------------------------
__global__ void x_to_bf16(const float* __restrict__ x, ushort* __restrict__ xb, int n4) {
    int i = blockIdx.x * blockDim.x + threadIdx.x;
    if (i >= n4) return;
    float4 v = *(const float4*)(x + (size_t)i * 4);
    ushort4 o;
    o.x = f2bf(v.x); o.y = f2bf(v.y); o.z = f2bf(v.z); o.w = f2bf(v.w);
    *(ushort4*)(xb + (size_t)i * 4) = o;
}

// ---------------------------------------------------------------------------
// bf16 MFMA GEMM: C[M,N] = A[M,K] @ Bt[N,K]^T + bias. (unchanged from R2)
// ---------------------------------------------------------------------------
template <int OUTMODE>
__global__ __launch_bounds__(256) void gemm_bt_mfma(
    const ushort* __restrict__ A, const ushort* __restrict__ Bt,
    const float* __restrict__ bias, void* __restrict__ Cout,
    ushort* __restrict__ Vt, int M, int N, int K) {
    __shared__ ushort As[128 * 40];
    __shared__ ushort Bs[128 * 40];
    const int tid = threadIdx.x;
    const int wid = tid >> 6, lane = tid & 63, quad = lane >> 4, l16 = lane & 15;
    const int row0 = blockIdx.y * 128, col0 = blockIdx.x * 128;
    const int mh = (wid >> 1) * 64, nh = (wid & 1) * 64;

    f32x4 acc[4][4] = {};

    for (int k0 = 0; k0 < K; k0 += 32) {
        __syncthreads();
#pragma unroll
        for (int rep = 0; rep < 2; ++rep) {
            int c = tid + rep * 256;
            int r = c >> 2, co = (c & 3) * 8;
            uint4 va = *(const uint4*)(A + (size_t)(row0 + r) * K + k0 + co);
            *(uint4*)&As[r * 40 + co] = va;
            uint4 vb = *(const uint4*)(Bt + (size_t)(col0 + r) * K + k0 + co);
            *(uint4*)&Bs[r * 40 + co] = vb;
        }
        __syncthreads();
        s16x8 af[4], bfr[4];
#pragma unroll
        for (int mi = 0; mi < 4; ++mi)
            af[mi] = *(const s16x8*)&As[(mh + mi * 16 + l16) * 40 + quad * 8];
#pragma unroll
        for (int ni = 0; ni < 4; ++ni)
            bfr[ni] = *(const s16x8*)&Bs[(nh + ni * 16 + l16) * 40 + quad * 8];
#pragma unroll
        for (int mi = 0; mi < 4; ++mi)
#pragma unroll
            for (int ni = 0; ni < 4; ++ni)
                acc[mi][ni] = __builtin_amdgcn_mfma_f32_16x16x32_bf16(
                    af[mi], bfr[ni], acc[mi][ni], 0, 0, 0);
    }

#pragma unroll
    for (int mi = 0; mi < 4; ++mi)
#pragma unroll
        for (int ni = 0; ni < 4; ++ni) {
            const int col = col0 + nh + ni * 16 + l16;
            const int rbase = row0 + mh + mi * 16 + quad * 4;
            const float bv = bias[col];
            if (OUTMODE == 0) {
                float* C = (float*)Cout;
#pragma unroll
                for (int j = 0; j < 4; ++j)
                    C[(size_t)(rbase + j) * N + col] = acc[mi][ni][j] + bv;
            } else {
                if (col < 2048) {
                    ushort* C = (ushort*)Cout;
#pragma unroll
                    for (int j = 0; j < 4; ++j)
                        C[(size_t)(rbase + j) * N + col] = f2bf(acc[mi][ni][j] + bv);
                } else {
                    const int bb = rbase >> 11;
                    const int seq = rbase & 2047;
                    const int d = col - 2048;
                    ushort4 pk;
                    pk.x = f2bf(acc[mi][ni][0] + bv);
                    pk.y = f2bf(acc[mi][ni][1] + bv);
                    pk.z = f2bf(acc[mi][ni][2] + bv);
                    pk.w = f2bf(acc[mi][ni][3] + bv);
                    *(ushort4*)&Vt[(size_t)bb * 2097152 + (size_t)d * 2048 + seq] = pk;
                }
            }
        }
}

// ---------------------------------------------------------------------------
// MFMA flash attention (unchanged from R2).
// ---------------------------------------------------------------------------
__global__ __launch_bounds__(256) void attn_fwd_mfma(
    const ushort* __restrict__ qkv, const ushort* __restrict__ Vt,
    ushort* __restrict__ ctx) {
    const int qb = blockIdx.x, h = blockIdx.y, b = blockIdx.z;
    const int tid = threadIdx.x;
    const int wid = tid >> 6, lane = tid & 63, quad = lane >> 4, l16 = lane & 15;

    __shared__ ushort Qs[128 * 72];
    __shared__ ushort Ks[64 * 72];
    __shared__ ushort Vts[64 * 72];
    __shared__ ushort Ps[128 * 72];

#pragma unroll
    for (int rep = 0; rep < 4; ++rep) {
        int c = tid + rep * 256;
        int r = c >> 3, co = (c & 7) * 8;
        uint4 v = *(const uint4*)(qkv + (size_t)(b * 2048 + qb * 128 + r) * 3072 + h * 64 + co);
        *(uint4*)&Qs[r * 72 + co] = v;
    }

    f32x4 o[2][4] = {};
    float m_r[2][4], l_r[2][4];
#pragma unroll
    for (int mi = 0; mi < 2; ++mi)
#pragma unroll
        for (int j = 0; j < 4; ++j) { m_r[mi][j] = -1e30f; l_r[mi][j] = 0.f; }

    for (int kt = 0; kt < SEQ_C / 64; ++kt) {
        __syncthreads();
#pragma unroll
        for (int rep = 0; rep < 2; ++rep) {
            int c = tid + rep * 256;
            int r = c >> 3, co = (c & 7) * 8;
            uint4 kv = *(const uint4*)(qkv + (size_t)(b * 2048 + kt * 64 + r) * 3072 + 1024 + h * 64 + co);
            *(uint4*)&Ks[r * 72 + co] = kv;
            uint4 vv = *(const uint4*)(Vt + (size_t)b * 2097152 + (size_t)(h * 64 + r) * 2048 + kt * 64 + co);
            *(uint4*)&Vts[r * 72 + co] = vv;
        }
        __syncthreads();

        f32x4 s[2][4] = {};
#pragma unroll
        for (int ks = 0; ks < 2; ++ks) {
            s16x8 qa[2], kb[4];
#pragma unroll
            for (int mi = 0; mi < 2; ++mi)
                qa[mi] = *(const s16x8*)&Qs[(wid * 32 + mi * 16 + l16) * 72 + ks * 32 + quad * 8];
#pragma unroll
            for (int ni = 0; ni < 4; ++ni)
                kb[ni] = *(const s16x8*)&Ks[(ni * 16 + l16) * 72 + ks * 32 + quad * 8];
#pragma unroll
            for (int mi = 0; mi < 2; ++mi)
#pragma unroll
                for (int ni = 0; ni < 4; ++ni)
                    s[mi][ni] = __builtin_amdgcn_mfma_f32_16x16x32_bf16(
                        qa[mi], kb[ni], s[mi][ni], 0, 0, 0);
        }
#pragma unroll
        for (int mi = 0; mi < 2; ++mi)
#pragma unroll
            for (int ni = 0; ni < 4; ++ni)
                s[mi][ni] *= 0.125f;

#pragma unroll
        for (int mi = 0; mi < 2; ++mi)
#pragma unroll
            for (int j = 0; j < 4; ++j) {
                float rm = fmaxf(fmaxf(s[mi][0][j], s[mi][1][j]),
                                 fmaxf(s[mi][2][j], s[mi][3][j]));
#pragma unroll
                for (int off = 1; off < 16; off <<= 1)
                    rm = fmaxf(rm, __shfl_xor(rm, off));
                const float mo = m_r[mi][j];
                const float mn = fmaxf(mo, rm);
                const float al = __expf(mo - mn);
                float ps = 0.f;
#pragma unroll
                for (int ni = 0; ni < 4; ++ni) {
                    float p = __expf(s[mi][ni][j] - mn);
                    s[mi][ni][j] = p;
                    ps += p;
                }
#pragma unroll
                for (int off = 1; off < 16; off <<= 1)
                    ps += __shfl_xor(ps, off);
                l_r[mi][j] = l_r[mi][j] * al + ps;
                m_r[mi][j] = mn;
#pragma unroll
                for (int nd = 0; nd < 4; ++nd) o[mi][nd][j] *= al;
                const int pr = wid * 32 + mi * 16 + quad * 4 + j;
#pragma unroll
                for (int ni = 0; ni < 4; ++ni)
                    Ps[pr * 72 + ni * 16 + l16] = f2bf(s[mi][ni][j]);
            }
        __syncthreads();

#pragma unroll
        for (int ks = 0; ks < 2; ++ks) {
            s16x8 pa[2], vb[4];
#pragma unroll
            for (int mi = 0; mi < 2; ++mi)
                pa[mi] = *(const s16x8*)&Ps[(wid * 32 + mi * 16 + l16) * 72 + ks * 32 + quad * 8];
#pragma unroll
            for (int nd = 0; nd < 4; ++nd)
                vb[nd] = *(const s16x8*)&Vts[(nd * 16 + l16) * 72 + ks * 32 + quad * 8];
#pragma unroll
            for (int mi = 0; mi < 2; ++mi)
#pragma unroll
                for (int nd = 0; nd < 4; ++nd)
                    o[mi][nd] = __builtin_amdgcn_mfma_f32_16x16x32_bf16(
                        pa[mi], vb[nd], o[mi][nd], 0, 0, 0);
        }
    }

#pragma unroll
    for (int mi = 0; mi < 2; ++mi)
#pragma unroll
        for (int j = 0; j < 4; ++j) {
            const float inv = 1.f / l_r[mi][j];
            const size_t row = (size_t)(b * 2048 + qb * 128 + wid * 32 + mi * 16 + quad * 4 + j);
#pragma unroll
            for (int nd = 0; nd < 4; ++nd)
                ctx[row * 1024 + h * 64 + nd * 16 + l16] = f2bf(o[mi][nd][j] * inv);
        }
}

// ---------------------------------------------------------------------------
// Workspace layout (MB offsets), total 78 MB:
//   [0,16M)   A0  (attn fft ping)    } reused: qkv bf16 [0,24M), Vt [24M,32M),
//   [16M,32M) A1  (attn fft pong)    }         ctx [32M,40M)
//   [32M,49M) H_a (16.78M; dead after pack -> ctx overlays safely)
//   [49M,54M) H_p (4.2M)
//   [54M,58M) P0   [58M,62M) P1
//   [62M,68M) WaT  [68M,70M) WpT  [70M,78M) x_bf
// ---------------------------------------------------------------------------
extern "C" void kernel_launch(void* const* d_in, const int* in_sizes, int n_in,
                              void* d_out, int out_size, void* d_ws, size_t ws_size,
                              hipStream_t stream) {
    const float* x        = (const float*)d_in[0];
    const float* attn_re  = (const float*)d_in[1];
    const float* attn_im  = (const float*)d_in[2];
    const int*   attn_idx = (const int*)d_in[3];
    const float* attn_sc  = (const float*)d_in[4];
    const float* proj_re  = (const float*)d_in[5];
    const float* proj_im  = (const float*)d_in[6];
    const int*   proj_idx = (const int*)d_in[7];
    const float* proj_sc  = (const float*)d_in[8];
    const float* attn_b   = (const float*)d_in[9];
    const float* proj_b   = (const float*)d_in[10];
    float* out = (float*)d_out;

    const size_t MB = 1048576;
    char* w = (char*)d_ws;
    float2* A0  = (float2*)(w);
    float2* A1  = (float2*)(w + 16 * MB);
    float2* Ha  = (float2*)(w + 32 * MB);
    float2* Hp  = (float2*)(w + 49 * MB);
    float2* P0  = (float2*)(w + 54 * MB);
    float2* P1  = (float2*)(w + 58 * MB);
    ushort* WaT = (ushort*)(w + 62 * MB);
    ushort* WpT = (ushort*)(w + 68 * MB);
    ushort* x_bf= (ushort*)(w + 70 * MB);
    ushort* qkvb= (ushort*)(w);
    ushort* Vt  = (ushort*)(w + 24 * MB);
    ushort* ctx = (ushort*)(w + 32 * MB);

    x_to_bf16<<<4096, 256, 0, stream>>>(x, x_bf, 1048576);

    hipMemsetAsync(Ha, 0, (size_t)(ATTN_NC + 1) * 8, stream);
    hipMemsetAsync(Hp, 0, (size_t)(PROJ_NC + 1) * 8, stream);
    scatter_half<<<ATTN_KEEP_C / 256, 256, 0, stream>>>(attn_re, attn_im, attn_idx, Ha, ATTN_KEEP_C);
    scatter_half<<<PROJ_KEEP_C / 256, 256, 0, stream>>>(proj_re, proj_im, proj_idx, Hp, PROJ_KEEP_C);

    // ---- attn: pack -> A0; ifft (1 r2 + 10 r4) ends in A1 ----
    pack_z<<<ATTN_NC / 256, 256, 0, stream>>>(Ha, A0, ATTN_NC, (float)(2.0 * M_PI / ATTN_PAD_C));
    fft_stage<<<(ATTN_NC / 2) / 256, 256, 0, stream>>>(A0, A1, 0, ATTN_NC / 2, ATTN_NC / 2);
    {
        float2* bufs[2] = {A1, A0};
        for (int i = 0; i < 10; ++i) {
            int slog = 1 + 2 * i;
            int M4 = ATTN_NC >> (slog + 2);
            fft_stage_r4<<<(ATTN_NC / 4) / 256, 256, 0, stream>>>(
                bufs[i & 1], bufs[1 - (i & 1)], slog, M4,
                (float)(M_PI / (2.0 * (double)M4)), ATTN_NC / 4);
        }
    }
    transpose_wz_bf16<<<dim3(3072 / 32, 1024 / 32), 256, 0, stream>>>(
        A1, WaT, 1024, 3072, 1.f / ATTN_PAD_C, attn_sc);

    // ---- proj: pack -> P0; ifft (1 r2 + 9 r4) ends in P0 ----
    pack_z<<<PROJ_NC / 256, 256, 0, stream>>>(Hp, P0, PROJ_NC, (float)(2.0 * M_PI / PROJ_PAD_C));
    fft_stage<<<(PROJ_NC / 2) / 256, 256, 0, stream>>>(P0, P1, 0, PROJ_NC / 2, PROJ_NC / 2);
    {
        float2* bufs[2] = {P1, P0};
        for (int i = 0; i < 9; ++i) {
            int slog = 1 + 2 * i;
            int M4 = PROJ_NC >> (slog + 2);
            fft_stage_r4<<<(PROJ_NC / 4) / 256, 256, 0, stream>>>(
                bufs[i & 1], bufs[1 - (i & 1)], slog, M4,
                (float)(M_PI / (2.0 * (double)M4)), PROJ_NC / 4);
        }
    }
    transpose_wz_bf16<<<dim3(1024 / 32, 1024 / 32), 256, 0, stream>>>(
        P0, WpT, 1024, 1024, 1.f / PROJ_PAD_C, proj_sc);

    // qkv = x @ Wa + bias (bf16 out; V third written transposed into Vt)
    gemm_bt_mfma<1><<<dim3(3072 / 128, 4096 / 128), 256, 0, stream>>>(
        x_bf, WaT, attn_b, qkvb, Vt, 4096, 3072, 1024);

    attn_fwd_mfma<<<dim3(SEQ_C / 128, N_HEADC, BATCH_C), 256, 0, stream>>>(qkvb, Vt, ctx);

    gemm_bt_mfma<0><<<dim3(1024 / 128, 4096 / 128), 256, 0, stream>>>(
        ctx, WpT, proj_b, out, (ushort*)nullptr, 4096, 1024, 1024);
}

// Round 4
// 420.040 us; speedup vs baseline: 4.1807x; 1.0666x over previous
//
#include <hip/hip_runtime.h>
#include <math.h>

#define N_HEADC  16
#define D_MODELC 1024
#define ATTN_N_C    3145728
#define ATTN_PAD_C  4194304
#define ATTN_NC     2097152   // half-size complex FFT length (2^21)
#define ATTN_KEEP_C 524288
#define PROJ_N_C    1048576
#define PROJ_PAD_C  1048576
#define PROJ_NC     524288    // 2^19
#define PROJ_KEEP_C 131072
#define BATCH_C 2
#define SEQ_C   2048

typedef __attribute__((ext_vector_type(8))) short s16x8;
typedef __attribute__((ext_vector_type(4))) float f32x4;

static __device__ __forceinline__ ushort f2bf(float f) {
    __bf16 b = (__bf16)f;
    return __builtin_bit_cast(ushort, b);
}
static __device__ __forceinline__ float2 cmul(float2 a, float2 b) {
    return make_float2(a.x * b.x - a.y * b.y, a.x * b.y + a.y * b.x);
}

// ---------------------------------------------------------------------------
// Scatter kept coeffs into zeroed HALF spectrum H[0..Nc].
// ---------------------------------------------------------------------------
__global__ void scatter_half(const float* __restrict__ re, const float* __restrict__ im,
                             const int* __restrict__ idx, float2* __restrict__ H, int keep) {
    int t = blockIdx.x * blockDim.x + threadIdx.x;
    if (t >= keep) return;
    H[idx[t]] = make_float2(re[t], im[t]);
}

// ---------------------------------------------------------------------------
// Pack half-spectrum H (len Nc+1) into Z (len Nc) for half-size complex iFFT.
// ---------------------------------------------------------------------------
__global__ void pack_z(const float2* __restrict__ H, float2* __restrict__ Z,
                       int Nc, float th0) {
    int k = blockIdx.x * blockDim.x + threadIdx.x;
    if (k >= Nc) return;
    float2 g = H[k];
    float2 hm = H[Nc - k];
    if (k == 0) { g.y = 0.f; hm.y = 0.f; }
    float2 gh = make_float2(hm.x, -hm.y);
    float2 sum = make_float2(g.x + gh.x, g.y + gh.y);
    float2 dif = make_float2(g.x - gh.x, g.y - gh.y);
    float si, co;
    sincosf(th0 * (float)k, &si, &co);
    float2 t = make_float2(dif.x * co - dif.y * si, dif.x * si + dif.y * co);
    Z[k] = make_float2(sum.x - t.y, sum.y + t.x);
}

// ---------------------------------------------------------------------------
// Radix-2 Stockham inverse stage (used once since log2(Nc) is odd).
// ---------------------------------------------------------------------------
__global__ void fft_stage(const float2* __restrict__ in, float2* __restrict__ out,
                          int slog, int m, int half) {
    int t = blockIdx.x * blockDim.x + threadIdx.x;
    if (t >= half) return;
    int s = 1 << slog;
    int q = t & (s - 1);
    int p = t >> slog;
    float si, co;
    sincosf((float)(M_PI / (double)m) * (float)p, &si, &co);
    float2 a = in[q + s * p];
    float2 b = in[q + s * (p + m)];
    float2 su = make_float2(a.x + b.x, a.y + b.y);
    float2 di = make_float2(a.x - b.x, a.y - b.y);
    int ob = q + ((s << 1) * p);
    out[ob]     = su;
    out[ob + s] = make_float2(di.x * co - di.y * si, di.x * si + di.y * co);
}

// ---------------------------------------------------------------------------
// Radix-4 Stockham inverse stage.
// ---------------------------------------------------------------------------
__global__ void fft_stage_r4(const float2* __restrict__ in, float2* __restrict__ out,
                             int slog, int M, float ang0, int quarter) {
    int t = blockIdx.x * blockDim.x + threadIdx.x;
    if (t >= quarter) return;
    int s = 1 << slog;
    int q = t & (s - 1);
    int p = t >> slog;
    float2 a0 = in[q + s * p];
    float2 a1 = in[q + s * (p + M)];
    float2 a2 = in[q + s * (p + 2 * M)];
    float2 a3 = in[q + s * (p + 3 * M)];
    float si, co;
    sincosf(ang0 * (float)p, &si, &co);
    float2 w  = make_float2(co, si);
    float2 w2 = cmul(w, w);
    float2 w3 = cmul(w2, w);
    float2 t0 = make_float2(a0.x + a2.x, a0.y + a2.y);
    float2 t1 = make_float2(a0.x - a2.x, a0.y - a2.y);
    float2 t2 = make_float2(a1.x + a3.x, a1.y + a3.y);
    float2 t3 = make_float2(a1.x - a3.x, a1.y - a3.y);
    float2 t3i = make_float2(-t3.y, t3.x);
    int ob = q + 4 * s * p;
    out[ob]         = make_float2(t0.x + t2.x, t0.y + t2.y);
    out[ob + s]     = cmul(w,  make_float2(t1.x + t3i.x, t1.y + t3i.y));
    out[ob + 2 * s] = cmul(w2, make_float2(t0.x - t2.x, t0.y - t2.y));
    out[ob + 3 * s] = cmul(w3, make_float2(t1.x - t3i.x, t1.y - t3i.y));
}

// ---------------------------------------------------------------------------
// Fused unpack + transpose + bf16 cast. x[j] = (j even ? Re : Im) z[j>>1].
// ---------------------------------------------------------------------------
__global__ __launch_bounds__(256) void transpose_wz_bf16(
    const float2* __restrict__ z, ushort* __restrict__ WT,
    int Kd, int Nd, float inv, const float* __restrict__ sc) {
    __shared__ float T[32][33];
    const int n0 = blockIdx.x * 32, k0 = blockIdx.y * 32;
    const int tx = threadIdx.x & 31, ty = threadIdx.x >> 5;
    const float s = inv * sc[0];
    for (int r = ty; r < 32; r += 8) {
        size_t j = (size_t)(k0 + r) * Nd + n0 + tx;
        float2 zz = z[j >> 1];
        T[r][tx] = (j & 1) ? zz.y : zz.x;
    }
    __syncthreads();
    for (int r = ty; r < 32; r += 8)
        WT[(size_t)(n0 + r) * Kd + k0 + tx] = f2bf(T[tx][r] * s);
}

// ---------------------------------------------------------------------------
// x (fp32) -> bf16
// ---------------------------------------------------------------------------
__global__ void x_to_bf16(const float* __restrict__ x, ushort* __restrict__ xb, int n4) {
    int i = blockIdx.x * blockDim.x + threadIdx.x;
    if (i >= n4) return;
    float4 v = *(const float4*)(x + (size_t)i * 4);
    ushort4 o;
    o.x = f2bf(v.x); o.y = f2bf(v.y); o.z = f2bf(v.z); o.w = f2bf(v.w);
    *(ushort4*)(xb + (size_t)i * 4) = o;
}

// ---------------------------------------------------------------------------
// bf16 MFMA GEMM: C[M,N] = A[M,K] @ Bt[N,K]^T + bias. (unchanged)
// ---------------------------------------------------------------------------
template <int OUTMODE>
__global__ __launch_bounds__(256) void gemm_bt_mfma(
    const ushort* __restrict__ A, const ushort* __restrict__ Bt,
    const float* __restrict__ bias, void* __restrict__ Cout,
    ushort* __restrict__ Vt, int M, int N, int K) {
    __shared__ ushort As[128 * 40];
    __shared__ ushort Bs[128 * 40];
    const int tid = threadIdx.x;
    const int wid = tid >> 6, lane = tid & 63, quad = lane >> 4, l16 = lane & 15;
    const int row0 = blockIdx.y * 128, col0 = blockIdx.x * 128;
    const int mh = (wid >> 1) * 64, nh = (wid & 1) * 64;

    f32x4 acc[4][4] = {};

    for (int k0 = 0; k0 < K; k0 += 32) {
        __syncthreads();
#pragma unroll
        for (int rep = 0; rep < 2; ++rep) {
            int c = tid + rep * 256;
            int r = c >> 2, co = (c & 3) * 8;
            uint4 va = *(const uint4*)(A + (size_t)(row0 + r) * K + k0 + co);
            *(uint4*)&As[r * 40 + co] = va;
            uint4 vb = *(const uint4*)(Bt + (size_t)(col0 + r) * K + k0 + co);
            *(uint4*)&Bs[r * 40 + co] = vb;
        }
        __syncthreads();
        s16x8 af[4], bfr[4];
#pragma unroll
        for (int mi = 0; mi < 4; ++mi)
            af[mi] = *(const s16x8*)&As[(mh + mi * 16 + l16) * 40 + quad * 8];
#pragma unroll
        for (int ni = 0; ni < 4; ++ni)
            bfr[ni] = *(const s16x8*)&Bs[(nh + ni * 16 + l16) * 40 + quad * 8];
#pragma unroll
        for (int mi = 0; mi < 4; ++mi)
#pragma unroll
            for (int ni = 0; ni < 4; ++ni)
                acc[mi][ni] = __builtin_amdgcn_mfma_f32_16x16x32_bf16(
                    af[mi], bfr[ni], acc[mi][ni], 0, 0, 0);
    }

#pragma unroll
    for (int mi = 0; mi < 4; ++mi)
#pragma unroll
        for (int ni = 0; ni < 4; ++ni) {
            const int col = col0 + nh + ni * 16 + l16;
            const int rbase = row0 + mh + mi * 16 + quad * 4;
            const float bv = bias[col];
            if (OUTMODE == 0) {
                float* C = (float*)Cout;
#pragma unroll
                for (int j = 0; j < 4; ++j)
                    C[(size_t)(rbase + j) * N + col] = acc[mi][ni][j] + bv;
            } else {
                if (col < 2048) {
                    ushort* C = (ushort*)Cout;
#pragma unroll
                    for (int j = 0; j < 4; ++j)
                        C[(size_t)(rbase + j) * N + col] = f2bf(acc[mi][ni][j] + bv);
                } else {
                    const int bb = rbase >> 11;
                    const int seq = rbase & 2047;
                    const int d = col - 2048;
                    ushort4 pk;
                    pk.x = f2bf(acc[mi][ni][0] + bv);
                    pk.y = f2bf(acc[mi][ni][1] + bv);
                    pk.z = f2bf(acc[mi][ni][2] + bv);
                    pk.w = f2bf(acc[mi][ni][3] + bv);
                    *(ushort4*)&Vt[(size_t)bb * 2097152 + (size_t)d * 2048 + seq] = pk;
                }
            }
        }
}

// ---------------------------------------------------------------------------
// MFMA flash attention, S^T formulation.
// S^T = K·Q^T puts qrow on the lane index (l16) and kpos on registers:
//   - softmax row reduce = in-lane over 16 regs + 2 shfl_xor (16,32)
//   - P written as packed ushort4 (ds_write_b64), wave-private (no barrier)
//   - PV as O^T = V^T·P^T, both operands b128 reads
// K/V staged via register prefetch: loads for kt+1 issue during compute of kt.
// 2 barriers per tile (was 3).
// ---------------------------------------------------------------------------
__global__ __launch_bounds__(256) void attn_fwd_mfma(
    const ushort* __restrict__ qkv, const ushort* __restrict__ Vt,
    ushort* __restrict__ ctx) {
    const int qb = blockIdx.x, h = blockIdx.y, b = blockIdx.z;
    const int tid = threadIdx.x;
    const int wid = tid >> 6, lane = tid & 63, quad = lane >> 4, l16 = lane & 15;
    const int wq = wid * 32;                   // wave's qrow base within block
    const float CEXP = 0.18033688011112042f;   // 0.125 * log2(e)

    __shared__ ushort Qs[128 * 72];
    __shared__ ushort Ks[64 * 72];
    __shared__ ushort Vts[64 * 72];   // [d][kpos]
    __shared__ ushort Ps[128 * 72];   // [qrow][kpos]

    // stage Q tile: 128 rows x 64 dims
#pragma unroll
    for (int rep = 0; rep < 4; ++rep) {
        int c = tid + rep * 256;
        int r = c >> 3, co = (c & 7) * 8;
        uint4 v = *(const uint4*)(qkv + (size_t)(b * 2048 + qb * 128 + r) * 3072 + h * 64 + co);
        *(uint4*)&Qs[r * 72 + co] = v;
    }

    // register prefetch of K/V tile 0
    uint4 kreg[2], vreg[2];
    {
        const int kt = 0;
#pragma unroll
        for (int rep = 0; rep < 2; ++rep) {
            int c = tid + rep * 256;
            int r = c >> 3, co = (c & 7) * 8;
            kreg[rep] = *(const uint4*)(qkv + (size_t)(b * 2048 + kt * 64 + r) * 3072 + 1024 + h * 64 + co);
            vreg[rep] = *(const uint4*)(Vt + (size_t)b * 2097152 + (size_t)(h * 64 + r) * 2048 + kt * 64 + co);
        }
    }

    f32x4 o[4][2] = {};     // [d-tile][qrow-tile], O^T layout
    float m_r[2], l_r[2];
    m_r[0] = m_r[1] = -1e30f;
    l_r[0] = l_r[1] = 0.f;

    for (int kt = 0; kt < SEQ_C / 64; ++kt) {
        __syncthreads();   // all waves done reading Ks/Vts of kt-1 (and Q staged, kt=0)
#pragma unroll
        for (int rep = 0; rep < 2; ++rep) {
            int c = tid + rep * 256;
            int r = c >> 3, co = (c & 7) * 8;
            *(uint4*)&Ks[r * 72 + co] = kreg[rep];
            *(uint4*)&Vts[r * 72 + co] = vreg[rep];
        }
        if (kt < SEQ_C / 64 - 1) {
            const int nt = kt + 1;
#pragma unroll
            for (int rep = 0; rep < 2; ++rep) {
                int c = tid + rep * 256;
                int r = c >> 3, co = (c & 7) * 8;
                kreg[rep] = *(const uint4*)(qkv + (size_t)(b * 2048 + nt * 64 + r) * 3072 + 1024 + h * 64 + co);
                vreg[rep] = *(const uint4*)(Vt + (size_t)b * 2097152 + (size_t)(h * 64 + r) * 2048 + nt * 64 + co);
            }
        }
        __syncthreads();   // Ks/Vts visible

        // S^T = K · Q^T : s[mi=kpos-tile][ni=qrow-tile]
        f32x4 s[4][2] = {};
#pragma unroll
        for (int ks = 0; ks < 2; ++ks) {
            s16x8 ka[4], qb_[2];
#pragma unroll
            for (int mi = 0; mi < 4; ++mi)
                ka[mi] = *(const s16x8*)&Ks[(mi * 16 + l16) * 72 + ks * 32 + quad * 8];
#pragma unroll
            for (int ni = 0; ni < 2; ++ni)
                qb_[ni] = *(const s16x8*)&Qs[(wq + ni * 16 + l16) * 72 + ks * 32 + quad * 8];
#pragma unroll
            for (int mi = 0; mi < 4; ++mi)
#pragma unroll
                for (int ni = 0; ni < 2; ++ni)
                    s[mi][ni] = __builtin_amdgcn_mfma_f32_16x16x32_bf16(
                        ka[mi], qb_[ni], s[mi][ni], 0, 0, 0);
        }

        // online softmax per qrow (= wq + ni*16 + l16); kpos = mi*16 + quad*4 + j
#pragma unroll
        for (int ni = 0; ni < 2; ++ni) {
            float rm = -1e30f;
#pragma unroll
            for (int mi = 0; mi < 4; ++mi)
#pragma unroll
                for (int j = 0; j < 4; ++j)
                    rm = fmaxf(rm, s[mi][ni][j]);
            rm = fmaxf(rm, __shfl_xor(rm, 16));
            rm = fmaxf(rm, __shfl_xor(rm, 32));
            const float mn = fmaxf(m_r[ni], rm);
            const float al = exp2f((m_r[ni] - mn) * CEXP);
            float ps = 0.f;
#pragma unroll
            for (int mi = 0; mi < 4; ++mi) {
                ushort4 pk;
#pragma unroll
                for (int j = 0; j < 4; ++j) {
                    float p = exp2f((s[mi][ni][j] - mn) * CEXP);
                    ps += p;
                    ((ushort*)&pk)[j] = f2bf(p);
                }
                *(ushort4*)&Ps[(wq + ni * 16 + l16) * 72 + mi * 16 + quad * 4] = pk;
            }
            ps += __shfl_xor(ps, 16);
            ps += __shfl_xor(ps, 32);
            l_r[ni] = l_r[ni] * al + ps;
            m_r[ni] = mn;
#pragma unroll
            for (int md = 0; md < 4; ++md)
#pragma unroll
                for (int j = 0; j < 4; ++j)
                    o[md][ni][j] *= al;
        }

        // O^T += V^T · P^T  (A = Vts[d][kpos], B = Ps[qrow][kpos]; wave-private P)
#pragma unroll
        for (int ks = 0; ks < 2; ++ks) {
            s16x8 va[4], pb[2];
#pragma unroll
            for (int md = 0; md < 4; ++md)
                va[md] = *(const s16x8*)&Vts[(md * 16 + l16) * 72 + ks * 32 + quad * 8];
#pragma unroll
            for (int ni = 0; ni < 2; ++ni)
                pb[ni] = *(const s16x8*)&Ps[(wq + ni * 16 + l16) * 72 + ks * 32 + quad * 8];
#pragma unroll
            for (int md = 0; md < 4; ++md)
#pragma unroll
                for (int ni = 0; ni < 2; ++ni)
                    o[md][ni] = __builtin_amdgcn_mfma_f32_16x16x32_bf16(
                        va[md], pb[ni], o[md][ni], 0, 0, 0);
        }
    }

    // epilogue: O^T[d][qrow] -> ctx[qrow][h*64+d], packed b64 stores
#pragma unroll
    for (int ni = 0; ni < 2; ++ni) {
        const float inv = 1.f / l_r[ni];
        const size_t row = (size_t)(b * 2048 + qb * 128 + wq + ni * 16 + l16);
#pragma unroll
        for (int md = 0; md < 4; ++md) {
            ushort4 pk;
#pragma unroll
            for (int j = 0; j < 4; ++j)
                ((ushort*)&pk)[j] = f2bf(o[md][ni][j] * inv);
            *(ushort4*)&ctx[row * 1024 + h * 64 + md * 16 + quad * 4] = pk;
        }
    }
}

// ---------------------------------------------------------------------------
// Workspace layout (MB offsets), total 78 MB:
//   [0,16M)   A0  (attn fft ping)    } reused: qkv bf16 [0,24M), Vt [24M,32M),
//   [16M,32M) A1  (attn fft pong)    }         ctx [32M,40M)
//   [32M,49M) H_a (dead after pack -> ctx overlays safely)
//   [49M,54M) H_p
//   [54M,58M) P0   [58M,62M) P1
//   [62M,68M) WaT  [68M,70M) WpT  [70M,78M) x_bf
// ---------------------------------------------------------------------------
extern "C" void kernel_launch(void* const* d_in, const int* in_sizes, int n_in,
                              void* d_out, int out_size, void* d_ws, size_t ws_size,
                              hipStream_t stream) {
    const float* x        = (const float*)d_in[0];
    const float* attn_re  = (const float*)d_in[1];
    const float* attn_im  = (const float*)d_in[2];
    const int*   attn_idx = (const int*)d_in[3];
    const float* attn_sc  = (const float*)d_in[4];
    const float* proj_re  = (const float*)d_in[5];
    const float* proj_im  = (const float*)d_in[6];
    const int*   proj_idx = (const int*)d_in[7];
    const float* proj_sc  = (const float*)d_in[8];
    const float* attn_b   = (const float*)d_in[9];
    const float* proj_b   = (const float*)d_in[10];
    float* out = (float*)d_out;

    const size_t MB = 1048576;
    char* w = (char*)d_ws;
    float2* A0  = (float2*)(w);
    float2* A1  = (float2*)(w + 16 * MB);
    float2* Ha  = (float2*)(w + 32 * MB);
    float2* Hp  = (float2*)(w + 49 * MB);
    float2* P0  = (float2*)(w + 54 * MB);
    float2* P1  = (float2*)(w + 58 * MB);
    ushort* WaT = (ushort*)(w + 62 * MB);
    ushort* WpT = (ushort*)(w + 68 * MB);
    ushort* x_bf= (ushort*)(w + 70 * MB);
    ushort* qkvb= (ushort*)(w);
    ushort* Vt  = (ushort*)(w + 24 * MB);
    ushort* ctx = (ushort*)(w + 32 * MB);

    x_to_bf16<<<4096, 256, 0, stream>>>(x, x_bf, 1048576);

    hipMemsetAsync(Ha, 0, (size_t)(ATTN_NC + 1) * 8, stream);
    hipMemsetAsync(Hp, 0, (size_t)(PROJ_NC + 1) * 8, stream);
    scatter_half<<<ATTN_KEEP_C / 256, 256, 0, stream>>>(attn_re, attn_im, attn_idx, Ha, ATTN_KEEP_C);
    scatter_half<<<PROJ_KEEP_C / 256, 256, 0, stream>>>(proj_re, proj_im, proj_idx, Hp, PROJ_KEEP_C);

    // ---- attn: pack -> A0; ifft (1 r2 + 10 r4) ends in A1 ----
    pack_z<<<ATTN_NC / 256, 256, 0, stream>>>(Ha, A0, ATTN_NC, (float)(2.0 * M_PI / ATTN_PAD_C));
    fft_stage<<<(ATTN_NC / 2) / 256, 256, 0, stream>>>(A0, A1, 0, ATTN_NC / 2, ATTN_NC / 2);
    {
        float2* bufs[2] = {A1, A0};
        for (int i = 0; i < 10; ++i) {
            int slog = 1 + 2 * i;
            int M4 = ATTN_NC >> (slog + 2);
            fft_stage_r4<<<(ATTN_NC / 4) / 256, 256, 0, stream>>>(
                bufs[i & 1], bufs[1 - (i & 1)], slog, M4,
                (float)(M_PI / (2.0 * (double)M4)), ATTN_NC / 4);
        }
    }
    transpose_wz_bf16<<<dim3(3072 / 32, 1024 / 32), 256, 0, stream>>>(
        A1, WaT, 1024, 3072, 1.f / ATTN_PAD_C, attn_sc);

    // ---- proj: pack -> P0; ifft (1 r2 + 9 r4) ends in P0 ----
    pack_z<<<PROJ_NC / 256, 256, 0, stream>>>(Hp, P0, PROJ_NC, (float)(2.0 * M_PI / PROJ_PAD_C));
    fft_stage<<<(PROJ_NC / 2) / 256, 256, 0, stream>>>(P0, P1, 0, PROJ_NC / 2, PROJ_NC / 2);
    {
        float2* bufs[2] = {P1, P0};
        for (int i = 0; i < 9; ++i) {
            int slog = 1 + 2 * i;
            int M4 = PROJ_NC >> (slog + 2);
            fft_stage_r4<<<(PROJ_NC / 4) / 256, 256, 0, stream>>>(
                bufs[i & 1], bufs[1 - (i & 1)], slog, M4,
                (float)(M_PI / (2.0 * (double)M4)), PROJ_NC / 4);
        }
    }
    transpose_wz_bf16<<<dim3(1024 / 32, 1024 / 32), 256, 0, stream>>>(
        P0, WpT, 1024, 1024, 1.f / PROJ_PAD_C, proj_sc);

    // qkv = x @ Wa + bias (bf16 out; V third written transposed into Vt)
    gemm_bt_mfma<1><<<dim3(3072 / 128, 4096 / 128), 256, 0, stream>>>(
        x_bf, WaT, attn_b, qkvb, Vt, 4096, 3072, 1024);

    attn_fwd_mfma<<<dim3(SEQ_C / 128, N_HEADC, BATCH_C), 256, 0, stream>>>(qkvb, Vt, ctx);

    gemm_bt_mfma<0><<<dim3(1024 / 128, 4096 / 128), 256, 0, stream>>>(
        ctx, WpT, proj_b, out, (ushort*)nullptr, 4096, 1024, 1024);
}